// Round 2
// baseline (301.338 us; speedup 1.0000x reference)
//
#include <hip/hip_runtime.h>

// VQ-VAE VectorQuantizer: B=32, C=D=64, H=W=64, K=512
// d_in[0]: inputs  [32,64,64,64] f32 (NCHW, C = embedding dim)
// d_in[1]: embedding [512,64] f32
// d_out: [loss(1) | out(32*64*64*64) | indices(32*4096)] all read as f32
//
// Numerics: the comparator recomputes the reference in numpy float32:
//   d_k = (x2 - 2*xe_k + e2_k)/64, argmin_k (first min)
// x2 ~ 64 while the code-dependent term is ~0.02, so the fp32 rounding of
// (x2 - 2*xe_k) quantizes comparisons at ulp(64)=7.6e-6. To match argmin we
// must replicate numpy's exact rounding: pairwise-8 sums for x2/e2 (squares
// rounded BEFORE adding -> fp contract off), then d = fl(fl(x2-2*xe)+e2).

#define KCODE 512
#define EMB   64
#define HWSZ  4096          // H*W
#define BATCH 32
#define NPOS  (BATCH * HWSZ) // 131072

// numpy pairwise_sum for n=64 (unrolled-by-8 pattern), squares NOT fused.
__device__ __forceinline__ float np_sumsq64(const float* a) {
    #pragma clang fp contract(off)
    {
        float r0 = a[0] * a[0], r1 = a[1] * a[1], r2 = a[2] * a[2], r3 = a[3] * a[3];
        float r4 = a[4] * a[4], r5 = a[5] * a[5], r6 = a[6] * a[6], r7 = a[7] * a[7];
        for (int i = 8; i < 64; i += 8) {
            r0 += a[i + 0] * a[i + 0];
            r1 += a[i + 1] * a[i + 1];
            r2 += a[i + 2] * a[i + 2];
            r3 += a[i + 3] * a[i + 3];
            r4 += a[i + 4] * a[i + 4];
            r5 += a[i + 5] * a[i + 5];
            r6 += a[i + 6] * a[i + 6];
            r7 += a[i + 7] * a[i + 7];
        }
        return ((r0 + r1) + (r2 + r3)) + ((r4 + r5) + (r6 + r7));
    }
}

// ws (float view): ws[0] = loss accumulator; ws[8..8+511] = ||e_k||^2 (np order)
__global__ void vq_precompute(const float* __restrict__ emb, float* __restrict__ ws) {
    int k = blockIdx.x * blockDim.x + threadIdx.x;
    if (k == 0) ws[0] = 0.0f;           // zero loss accumulator (d_ws is poisoned)
    if (k < KCODE) {
        ws[8 + k] = np_sumsq64(emb + k * EMB);
    }
}

__global__ __launch_bounds__(256) void vq_main(
        const float* __restrict__ in,      // [32,64,4096]
        const float* __restrict__ emb,     // [512,64]
        const float* __restrict__ e2,      // ws+8, [512]
        float* __restrict__ loss_accum,    // ws+0
        float* __restrict__ out_q,         // d_out+1, [32,64,4096]
        float* __restrict__ out_idx) {     // d_out+1+NPOS*EMB, [NPOS]
    const int n  = blockIdx.x * 256 + threadIdx.x;   // position id
    const int b  = n >> 12;                          // / 4096
    const int hw = n & (HWSZ - 1);

    // Load this position's 64-dim vector (stride HWSZ between components;
    // coalesced across lanes since lanes have consecutive hw).
    const float* xp = in + (size_t)b * (EMB * HWSZ) + hw;
    float x[EMB];
    #pragma unroll
    for (int c = 0; c < EMB; ++c) x[c] = xp[(size_t)c * HWSZ];

    // x2 with numpy's exact summation pattern
    const float x2 = np_sumsq64(x);

    // argmin_k fl(fl(x2 - 2*xe_k) + e2_k); k wave-uniform -> emb reads scalar.
    int   best  = 0;
    float bestD = 3.4e38f;
    for (int k = 0; k < KCODE; ++k) {
        const float* ek = emb + k * EMB;
        float t0 = 0.f, t1 = 0.f, t2 = 0.f, t3 = 0.f;
        #pragma unroll
        for (int c = 0; c < EMB; c += 4) {
            t0 = fmaf(x[c + 0], ek[c + 0], t0);
            t1 = fmaf(x[c + 1], ek[c + 1], t1);
            t2 = fmaf(x[c + 2], ek[c + 2], t2);
            t3 = fmaf(x[c + 3], ek[c + 3], t3);
        }
        float xe = (t0 + t1) + (t2 + t3);
        // 2*xe is exact in fp32, so fma-contraction here is rounding-identical.
        float tmp = x2 - 2.0f * xe;      // fl(x2 - 2*xe): the ulp(64) quantizer
        float d   = tmp + e2[k];         // fl(tmp + e2)
        if (d < bestD) { bestD = d; best = k; }   // strict <: first min kept
    }

    // Quantized output (forward value of straight-through = embedding row),
    // plus per-thread sum of (q - x)^2 for the loss.
    const float4* qk = (const float4*)(emb + (size_t)best * EMB);
    float* op = out_q + (size_t)b * (EMB * HWSZ) + hw;
    float s = 0.0f;
    #pragma unroll
    for (int c4 = 0; c4 < EMB / 4; ++c4) {
        float4 v = qk[c4];
        float d0 = v.x - x[c4 * 4 + 0];
        float d1 = v.y - x[c4 * 4 + 1];
        float d2 = v.z - x[c4 * 4 + 2];
        float d3 = v.w - x[c4 * 4 + 3];
        s = fmaf(d0, d0, s); s = fmaf(d1, d1, s);
        s = fmaf(d2, d2, s); s = fmaf(d3, d3, s);
        op[(size_t)(c4 * 4 + 0) * HWSZ] = v.x;
        op[(size_t)(c4 * 4 + 1) * HWSZ] = v.y;
        op[(size_t)(c4 * 4 + 2) * HWSZ] = v.z;
        op[(size_t)(c4 * 4 + 3) * HWSZ] = v.w;
    }
    out_idx[n] = (float)best;

    // Block-level loss reduction: wave shuffle -> LDS -> one atomic per block.
    #pragma unroll
    for (int off = 32; off > 0; off >>= 1)
        s += __shfl_down(s, off, 64);
    __shared__ float red[4];
    const int wave = threadIdx.x >> 6;
    const int lane = threadIdx.x & 63;
    if (lane == 0) red[wave] = s;
    __syncthreads();
    if (threadIdx.x == 0) {
        float bs = (red[0] + red[1]) + (red[2] + red[3]);
        atomicAdd(loss_accum, bs);
    }
}

__global__ void vq_finalize(const float* __restrict__ loss_accum,
                            float* __restrict__ out0) {
    // loss = q_latent + 0.25*e_latent = 1.25 * mean((q - x)^2)
    out0[0] = 1.25f * loss_accum[0] * (1.0f / ((float)NPOS * (float)EMB));
}

extern "C" void kernel_launch(void* const* d_in, const int* in_sizes, int n_in,
                              void* d_out, int out_size, void* d_ws, size_t ws_size,
                              hipStream_t stream) {
    const float* in  = (const float*)d_in[0];
    const float* emb = (const float*)d_in[1];
    float* ws   = (float*)d_ws;
    float* out  = (float*)d_out;

    float* loss_accum = ws;            // ws[0]
    float* e2         = ws + 8;        // ws[8..519]
    float* out_loss   = out;           // [1]
    float* out_q      = out + 1;       // [NPOS*EMB]
    float* out_idx    = out + 1 + (size_t)NPOS * EMB;  // [NPOS]

    vq_precompute<<<2, 256, 0, stream>>>(emb, ws);
    vq_main<<<NPOS / 256, 256, 0, stream>>>(in, emb, e2, loss_accum, out_q, out_idx);
    vq_finalize<<<1, 1, 0, stream>>>(loss_accum, out_loss);
}